// Round 15
// baseline (29.815 us; speedup 1.0000x reference)
//
#include <hip/hip_runtime.h>
#include <hip/hip_fp16.h>

#define SR   9
#define SD   19
#define TW   24                 // tile width (pixels)
#define TH   4                  // tile height (pixels)
#define LW   (TW + 2*SR)        // 42 staged cols
#define LH   (TH + 2*SR)        // 22 staged rows
#define LSH  48                 // LDS row stride in halves (96B: 8B-aligned rows)
#define IMG  192
#define NPIX (IMG*IMG)

typedef __fp16 h2 __attribute__((ext_vector_type(2)));

// Block = 384 threads: 24 quad-slots (6 quad-cols x 4 rows) x 16 dy-groups.
// Grid 8x48x2 = 768 blocks = exactly 3/CU. Tile in LDS as fp16 (stride 48
// halves): ds_read_b64 = 4 taps -> 6 reads/row serve a 4-pixel quad.
// Inner math packed fp16: packs (p0,p1),(p2,p3); per dx 18 packed ops for
// 4 px-taps. Range kernel = shifted cubic (k=c^2 folded per pixel),
// w = max(cx*p, 0) (upper clamp inert: p <= 0.3145 < 1).
__global__ __launch_bounds__(384) void ms_iter(const float* __restrict__ in,
                                               float* __restrict__ out) {
    __shared__ __align__(16) __fp16 tile[LH * LSH];
    __shared__ float4 pnum[16][24], pden[16][24];

    const int b   = blockIdx.z;
    const int bx0 = blockIdx.x * TW;
    const int by0 = blockIdx.y * TH;
    const float* __restrict__ img = in + b * NPIX;

    const int tid = threadIdx.x;      // 0..383
    const int tz  = tid / 24;         // 0..15  dy group
    const int s   = tid - 24 * tz;    // 0..23  quad slot
    const int qx  = s % 6;            // quad col
    const int ty  = s / 6;            // pixel row 0..3

    // stage padded tile (replication pad via clamp), f32 -> fp16
    for (int i = tid; i < LH * LW; i += 384) {
        int r  = i / LW, c = i - r * LW;
        int gy = min(max(by0 + r - SR, 0), IMG - 1);
        int gx = min(max(bx0 + c - SR, 0), IMG - 1);
        tile[r * LSH + c] = (__fp16)img[gy * IMG + gx];
    }
    __syncthreads();

    constexpr float CXf[SD] = {
        0.5697829f, 0.6411806f, 0.7115726f, 0.7788008f, 0.8406238f,
        0.8948393f, 0.9394131f, 0.9726045f, 0.9930797f, 1.0000000f,
        0.9930797f, 0.9726045f, 0.9394131f, 0.8948393f, 0.8406238f,
        0.7788008f, 0.7115726f, 0.6411806f, 0.5697829f
    };
    const float a3 = -0.8285240f;   // cubic for A*exp(-2t)-B

    const int x0 = 4 * qx;
    float c[4];
#pragma unroll
    for (int p = 0; p < 4; ++p)
        c[p] = (float)tile[(ty + SR) * LSH + x0 + SR + p];

    // per-pixel shifted cubic coefficients (k=c^2), packed (p0,p1) & (p2,p3)
    float m2c[4], c2[4], c1[4], c0[4];
#pragma unroll
    for (int p = 0; p < 4; ++p) {
        float k = c[p] * c[p];
        m2c[p] = -2.f * c[p];
        c2[p]  = k * -2.4855720f + 1.5534825f;
        c1[p]  = (k * -2.4855720f + 3.1069650f) * k + -1.5923197f;
        c0[p]  = ((k * a3 + 1.5534825f) * k + -1.5923197f) * k + 0.3138366f;
    }
    const h2 m2c01 = __builtin_amdgcn_cvt_pkrtz(m2c[0], m2c[1]);
    const h2 m2c23 = __builtin_amdgcn_cvt_pkrtz(m2c[2], m2c[3]);
    const h2 c2_01 = __builtin_amdgcn_cvt_pkrtz(c2[0], c2[1]);
    const h2 c2_23 = __builtin_amdgcn_cvt_pkrtz(c2[2], c2[3]);
    const h2 c1_01 = __builtin_amdgcn_cvt_pkrtz(c1[0], c1[1]);
    const h2 c1_23 = __builtin_amdgcn_cvt_pkrtz(c1[2], c1[3]);
    const h2 c0_01 = __builtin_amdgcn_cvt_pkrtz(c0[0], c0[1]);
    const h2 c0_23 = __builtin_amdgcn_cvt_pkrtz(c0[2], c0[3]);
    const h2 a3_2  = { (__fp16)(-0.8285240f), (__fp16)(-0.8285240f) };
    const h2 zero2 = { (__fp16)0.f, (__fp16)0.f };

    // dy rows per tz: tz 0..2 -> 2 rows (0..5), tz 3..15 -> 1 row (6..18).
    // wave0 (tz0,1,2-part) uniform 2; wave1 mixes 2|1; waves 2-5 uniform 1.
    const int beg = (tz < 3) ? 2 * tz : (tz + 3);

    float num[4] = {0.f, 0.f, 0.f, 0.f}, den[4] = {0.f, 0.f, 0.f, 0.f};

    auto row_body = [&](int dy) {
        const float ft = (float)(dy - SR);
        const float fy = __builtin_amdgcn_exp2f(ft * ft * -0.010018715f);

        // 6 x ds_read_b64 (8B-aligned: base = 96*row + 8*qx bytes)
        const uint2* q2 = reinterpret_cast<const uint2*>(&tile[(ty + dy) * LSH + x0]);
        unsigned hp[12];
#pragma unroll
        for (int j = 0; j < 6; ++j) { uint2 v = q2[j]; hp[2*j] = v.x; hp[2*j+1] = v.y; }
        unsigned al[10];
#pragma unroll
        for (int j = 0; j < 10; ++j)
            al[j] = __builtin_amdgcn_alignbit(hp[j + 1], hp[j], 16);

        h2 rn01 = zero2, rd01 = zero2, rn23 = zero2, rd23 = zero2;
#pragma unroll
        for (int dx = 0; dx < SD; ++dx) {
            // n-pairs: (w[dx],w[dx+1]) and (w[dx+2],w[dx+3])
            unsigned u01 = (dx & 1) ? al[dx >> 1] : hp[dx >> 1];
            unsigned u23 = (dx & 1) ? al[(dx >> 1) + 1] : hp[(dx >> 1) + 1];
            h2 n01 = __builtin_bit_cast(h2, u01);
            h2 n23 = __builtin_bit_cast(h2, u23);
            h2 cx  = { (__fp16)CXf[dx], (__fp16)CXf[dx] };

            h2 t01 = m2c01 * n01 + n01 * n01;   // t' = n^2 - 2cn (pk_mul+pk_fma)
            h2 t23 = m2c23 * n23 + n23 * n23;
            h2 p01 = a3_2 * t01 + c2_01;        // Horner
            h2 p23 = a3_2 * t23 + c2_23;
            p01 = p01 * t01 + c1_01;  p23 = p23 * t23 + c1_23;
            p01 = p01 * t01 + c0_01;  p23 = p23 * t23 + c0_23;
            h2 w01 = __builtin_elementwise_max(p01 * cx, zero2);
            h2 w23 = __builtin_elementwise_max(p23 * cx, zero2);
            rn01 = w01 * n01 + rn01;  rd01 = rd01 + w01;
            rn23 = w23 * n23 + rn23;  rd23 = rd23 + w23;
        }
        num[0] += fy * (float)rn01[0];  den[0] += fy * (float)rd01[0];
        num[1] += fy * (float)rn01[1];  den[1] += fy * (float)rd01[1];
        num[2] += fy * (float)rn23[0];  den[2] += fy * (float)rd23[0];
        num[3] += fy * (float)rn23[1];  den[3] += fy * (float)rd23[1];
    };

    row_body(beg);
    if (tz < 3) row_body(beg + 1);

    pnum[tz][s] = make_float4(num[0], num[1], num[2], num[3]);
    pden[tz][s] = make_float4(den[0], den[1], den[2], den[3]);
    __syncthreads();

    // final combine: 24 threads, one quad each, float4 coalesced store
    if (tid < 24) {
        float4 n = make_float4(0.f, 0.f, 0.f, 0.f);
        float4 d = make_float4(0.f, 0.f, 0.f, 0.f);
#pragma unroll
        for (int g = 0; g < 16; ++g) {
            float4 a = pnum[g][tid], e = pden[g][tid];
            n.x += a.x; n.y += a.y; n.z += a.z; n.w += a.w;
            d.x += e.x; d.y += e.y; d.z += e.z; d.w += e.w;
        }
        const float K = 0.04701581f;   // spatial amplitude 1/(SSIGMA*sqrt(2pi))
        float4 o;
        o.x = (K * n.x) / (K * d.x + 1e-8f);
        o.y = (K * n.y) / (K * d.y + 1e-8f);
        o.z = (K * n.z) / (K * d.z + 1e-8f);
        o.w = (K * n.w) / (K * d.w + 1e-8f);
        const int oqx = tid % 6, oty = tid / 6;
        *reinterpret_cast<float4*>(&out[b * NPIX + (by0 + oty) * IMG + bx0 + 4 * oqx]) = o;
    }
}

extern "C" void kernel_launch(void* const* d_in, const int* in_sizes, int n_in,
                              void* d_out, int out_size, void* d_ws, size_t ws_size,
                              hipStream_t stream) {
    const float* in  = (const float*)d_in[0];
    float*       out = (float*)d_out;
    float*       ws  = (float*)d_ws;   // needs 2*192*192*4 = 294912 bytes

    dim3 grid(IMG / TW, IMG / TH, 2);   // 8 x 48 x 2 = 768 blocks = 3/CU exact
    dim3 block(384, 1, 1);              // 6 waves

    ms_iter<<<grid, block, 0, stream>>>(in, out);   // iter 1
    ms_iter<<<grid, block, 0, stream>>>(out, ws);   // iter 2
    ms_iter<<<grid, block, 0, stream>>>(ws, out);   // iter 3
}